// Round 1
// baseline (1367.253 us; speedup 1.0000x reference)
//
#include <hip/hip_runtime.h>
#include <math.h>
#include <limits.h>

#define D 512
#define C 17
#define EQ_CAP 2048

// ---------------------------------------------------------------------------
// K1: logits -> entropy + argmax per batch row
// ---------------------------------------------------------------------------
__global__ __launch_bounds__(256) void k_classify(
    const float* __restrict__ feature, const float* __restrict__ clf_w,
    const float* __restrict__ clf_b, float* __restrict__ ent_new,
    int* __restrict__ yhat, int B)
{
    __shared__ float w_s[C * D];
    __shared__ float b_s[C];
    int tid = threadIdx.x;
    for (int i = tid; i < C * D; i += 256) w_s[i] = clf_w[i];
    if (tid < C) b_s[tid] = clf_b[tid];
    __syncthreads();
    int wave = tid >> 6, lane = tid & 63;
    for (int row = blockIdx.x * 4 + wave; row < B; row += gridDim.x * 4) {
        const float* f = feature + (size_t)row * D;
        float4 f0 = *(const float4*)(f + lane * 8);
        float4 f1 = *(const float4*)(f + lane * 8 + 4);
        double p[C];
        for (int c = 0; c < C; ++c) {
            const float* w = w_s + c * D + lane * 8;
            double s = (double)f0.x * w[0] + (double)f0.y * w[1] +
                       (double)f0.z * w[2] + (double)f0.w * w[3] +
                       (double)f1.x * w[4] + (double)f1.y * w[5] +
                       (double)f1.z * w[6] + (double)f1.w * w[7];
            for (int m = 32; m; m >>= 1) s += __shfl_xor(s, m, 64);
            p[c] = s + (double)b_s[c];
        }
        if (lane == 0) {
            double mx = p[0]; int am = 0;
            for (int c = 1; c < C; ++c) if (p[c] > mx) { mx = p[c]; am = c; }
            double Z = 0.0, S = 0.0;
            for (int c = 0; c < C; ++c) {
                double e = exp(p[c] - mx);
                Z += e; S += e * (p[c] - mx);
            }
            double ent = log(Z) - S / Z;   // >= 0 always
            ent_new[row] = (float)ent;
            yhat[row] = am;
        }
    }
}

// ---------------------------------------------------------------------------
// iterate over all NT concatenated elements, vectorized 4-wide
// f(index, label, entropy_bits)
// ---------------------------------------------------------------------------
template <typename F>
__device__ inline void for_all_elems(int tid, int N, int NT,
    const float* __restrict__ eb, const int* __restrict__ lb,
    const float* __restrict__ en, const int* __restrict__ yh, F&& f)
{
    int nchunk = NT >> 2;
    for (int j = tid; j < nchunk; j += 256) {
        int base = j << 2;
        if (base + 4 <= N) {
            int4 y4 = *(const int4*)(lb + base);
            float4 e4 = *(const float4*)(eb + base);
            f(base + 0, y4.x, __float_as_uint(e4.x));
            f(base + 1, y4.y, __float_as_uint(e4.y));
            f(base + 2, y4.z, __float_as_uint(e4.z));
            f(base + 3, y4.w, __float_as_uint(e4.w));
        } else if (base >= N) {
            int4 y4 = *(const int4*)(yh + base - N);
            float4 e4 = *(const float4*)(en + base - N);
            f(base + 0, y4.x, __float_as_uint(e4.x));
            f(base + 1, y4.y, __float_as_uint(e4.y));
            f(base + 2, y4.z, __float_as_uint(e4.z));
            f(base + 3, y4.w, __float_as_uint(e4.w));
        } else {
            for (int k = 0; k < 4; ++k) {
                int i = base + k;
                int y = (i < N) ? lb[i] : yh[i - N];
                unsigned b = __float_as_uint((i < N) ? eb[i] : en[i - N]);
                f(i, y, b);
            }
        }
    }
    for (int i = (nchunk << 2) + tid; i < NT; i += 256) {
        int y = (i < N) ? lb[i] : yh[i - N];
        unsigned b = __float_as_uint((i < N) ? eb[i] : en[i - N]);
        f(i, y, b);
    }
}

// ---------------------------------------------------------------------------
// K2: per-class exact K-th-smallest entropy (radix select on float bits,
// 4 x 8-bit levels) + exact index tie-break. One block per class.
// Also zeroes this class's slice of Wc.
// ---------------------------------------------------------------------------
__global__ __launch_bounds__(256) void k_select(
    const float* __restrict__ ent_bank, const int* __restrict__ labels,
    const float* __restrict__ ent_new, const int* __restrict__ yhat,
    const int* __restrict__ fk, int N, int B,
    unsigned* __restrict__ class_v, int* __restrict__ class_thr,
    float* __restrict__ Wc)
{
    __shared__ unsigned hist[256];
    __shared__ unsigned scan[256];
    __shared__ int eq_list[EQ_CAP];
    __shared__ unsigned eq_cnt;
    __shared__ int s_bucket;
    __shared__ unsigned s_excl;
    __shared__ int s_thr;

    int c = blockIdx.x;
    int tid = threadIdx.x;

    for (int d = tid; d < D; d += 256) Wc[c * D + d] = 0.f;

    int K = fk[0];
    int NT = N + B;
    unsigned prefix = 0;
    int Krem = K;
    bool select_all = false;

    for (int level = 0; level < 4; ++level) {
        hist[tid] = 0;
        __syncthreads();
        int shift = 24 - 8 * level;
        for_all_elems(tid, N, NT, ent_bank, labels, ent_new, yhat,
            [&](int i, int y, unsigned b) {
                (void)i;
                if (y != c) return;
                if (level > 0 && (b >> (shift + 8)) != prefix) return;
                atomicAdd(&hist[(b >> shift) & 255u], 1u);
            });
        __syncthreads();
        scan[tid] = hist[tid];
        __syncthreads();
        for (int off = 1; off < 256; off <<= 1) {
            unsigned v = scan[tid];
            if (tid >= off) v += scan[tid - off];
            __syncthreads();
            scan[tid] = v;
            __syncthreads();
        }
        if (level == 0 && (int)scan[255] <= K) {  // class has <= K members
            select_all = true;                    // uniform decision
            break;
        }
        unsigned incl = scan[tid];
        unsigned excl = incl - hist[tid];
        if ((int)excl < Krem && Krem <= (int)incl) {
            s_bucket = tid; s_excl = excl;        // exactly one writer
        }
        __syncthreads();
        prefix = (prefix << 8) | (unsigned)s_bucket;
        Krem -= (int)s_excl;
        __syncthreads();
    }

    if (select_all) {
        if (tid == 0) { class_v[c] = 0xFFFFFFFFu; class_thr[c] = INT_MAX; }
        return;
    }

    unsigned v = prefix;   // exact K-th smallest entropy bit pattern
    if (tid == 0) eq_cnt = 0;
    __syncthreads();
    for_all_elems(tid, N, NT, ent_bank, labels, ent_new, yhat,
        [&](int i, int y, unsigned b) {
            if (y != c || b != v) return;
            unsigned pos = atomicAdd(&eq_cnt, 1u);
            if (pos < EQ_CAP) eq_list[pos] = i;
        });
    __syncthreads();
    int n_eq = (int)min(eq_cnt, (unsigned)EQ_CAP);
    // include the Krem smallest indices among equal-valued elements
    for (int j = tid; j < n_eq; j += 256) {
        int mine = eq_list[j];
        int r = 0;
        for (int k2 = 0; k2 < n_eq; ++k2) r += (eq_list[k2] < mine);
        if (r == Krem - 1) s_thr = mine;          // exactly one writer
    }
    __syncthreads();
    if (tid == 0) { class_v[c] = v; class_thr[c] = s_thr; }
}

// ---------------------------------------------------------------------------
// K3: sum normalized selected rows into Wc. One wave per row.
// predicate: bits < v[c]  ||  (bits == v[c] && idx <= thr[c])
// ---------------------------------------------------------------------------
__global__ __launch_bounds__(256) void k_rowsum(
    const float* __restrict__ supports, const float* __restrict__ feature,
    const float* __restrict__ ent_bank, const int* __restrict__ labels,
    const float* __restrict__ ent_new, const int* __restrict__ yhat,
    const unsigned* __restrict__ class_v, const int* __restrict__ class_thr,
    float* __restrict__ Wc, int N, int NT)
{
    int r = blockIdx.x * 4 + (threadIdx.x >> 6);
    if (r >= NT) return;
    int lane = threadIdx.x & 63;
    int c = (r < N) ? labels[r] : yhat[r - N];
    unsigned b = __float_as_uint((r < N) ? ent_bank[r] : ent_new[r - N]);
    unsigned v = class_v[c];
    bool sel = (b < v) || (b == v && r <= class_thr[c]);
    if (!sel) return;
    const float* x = (r < N) ? (supports + (size_t)r * D)
                             : (feature + (size_t)(r - N) * D);
    float4 a = *(const float4*)(x + lane * 8);
    float4 d4 = *(const float4*)(x + lane * 8 + 4);
    float ss = a.x * a.x + a.y * a.y + a.z * a.z + a.w * a.w +
               d4.x * d4.x + d4.y * d4.y + d4.z * d4.z + d4.w * d4.w;
    for (int m = 32; m; m >>= 1) ss += __shfl_xor(ss, m, 64);
    float inv = 1.f / fmaxf(sqrtf(ss), 1e-12f);
    float* w = Wc + c * D + lane * 8;
    atomicAdd(w + 0, a.x * inv);  atomicAdd(w + 1, a.y * inv);
    atomicAdd(w + 2, a.z * inv);  atomicAdd(w + 3, a.w * inv);
    atomicAdd(w + 4, d4.x * inv); atomicAdd(w + 5, d4.y * inv);
    atomicAdd(w + 6, d4.z * inv); atomicAdd(w + 7, d4.w * inv);
}

// ---------------------------------------------------------------------------
// K4: per-class (column) normalization of Wc -> wn
// ---------------------------------------------------------------------------
__global__ __launch_bounds__(256) void k_colnorm(
    const float* __restrict__ Wc, float* __restrict__ wn)
{
    __shared__ float red[4];
    __shared__ float s_inv;
    int tid = threadIdx.x, wave = tid >> 6, lane = tid & 63;
    for (int c = 0; c < C; ++c) {
        float ss = 0.f;
        for (int d = tid; d < D; d += 256) { float x = Wc[c * D + d]; ss += x * x; }
        for (int m = 32; m; m >>= 1) ss += __shfl_xor(ss, m, 64);
        if (lane == 0) red[wave] = ss;
        __syncthreads();
        if (tid == 0) {
            float t = red[0] + red[1] + red[2] + red[3];
            s_inv = 1.f / fmaxf(sqrtf(t), 1e-12f);
        }
        __syncthreads();
        for (int d = tid; d < D; d += 256) wn[c * D + d] = Wc[c * D + d] * s_inv;
        __syncthreads();
    }
}

// ---------------------------------------------------------------------------
// K5: out = feature @ wn^T
// ---------------------------------------------------------------------------
__global__ __launch_bounds__(256) void k_out(
    const float* __restrict__ feature, const float* __restrict__ wn,
    float* __restrict__ out, int B)
{
    __shared__ float w_s[C * D];
    int tid = threadIdx.x;
    for (int i = tid; i < C * D; i += 256) w_s[i] = wn[i];
    __syncthreads();
    int wave = tid >> 6, lane = tid & 63;
    for (int row = blockIdx.x * 4 + wave; row < B; row += gridDim.x * 4) {
        const float* f = feature + (size_t)row * D;
        float4 f0 = *(const float4*)(f + lane * 8);
        float4 f1 = *(const float4*)(f + lane * 8 + 4);
        for (int c = 0; c < C; ++c) {
            const float* w = w_s + c * D + lane * 8;
            float s = f0.x * w[0] + f0.y * w[1] + f0.z * w[2] + f0.w * w[3] +
                      f1.x * w[4] + f1.y * w[5] + f1.z * w[6] + f1.w * w[7];
            for (int m = 32; m; m >>= 1) s += __shfl_xor(s, m, 64);
            if (lane == 0) out[(size_t)row * C + c] = s;
        }
    }
}

// ---------------------------------------------------------------------------
extern "C" void kernel_launch(void* const* d_in, const int* in_sizes, int n_in,
                              void* d_out, int out_size, void* d_ws, size_t ws_size,
                              hipStream_t stream)
{
    (void)n_in; (void)out_size; (void)ws_size;
    const float* feature  = (const float*)d_in[0];
    const float* clf_w    = (const float*)d_in[1];
    const float* clf_b    = (const float*)d_in[2];
    const float* supports = (const float*)d_in[3];
    const float* ent_bank = (const float*)d_in[4];
    const int*   labels   = (const int*)d_in[5];
    const int*   fk       = (const int*)d_in[6];
    int B  = in_sizes[0] / D;
    int N  = in_sizes[4];
    int NT = N + B;

    char* ws = (char*)d_ws;
    size_t o = 0;
    auto align256 = [&](size_t x) { return (x + 255) & ~(size_t)255; };
    float*    ent_new  = (float*)(ws + o);  o = align256(o + (size_t)B * 4);
    int*      yhat     = (int*)(ws + o);    o = align256(o + (size_t)B * 4);
    unsigned* class_v  = (unsigned*)(ws + o); o = align256(o + 32 * 4);
    int*      class_thr= (int*)(ws + o);    o = align256(o + 32 * 4);
    float*    Wc       = (float*)(ws + o);  o = align256(o + (size_t)C * D * 4);
    float*    wn       = (float*)(ws + o);  o = align256(o + (size_t)C * D * 4);
    float*    out      = (float*)d_out;

    int cb = (B + 3) / 4; if (cb > 1024) cb = 1024;

    k_classify<<<cb, 256, 0, stream>>>(feature, clf_w, clf_b, ent_new, yhat, B);
    k_select<<<C, 256, 0, stream>>>(ent_bank, labels, ent_new, yhat, fk, N, B,
                                    class_v, class_thr, Wc);
    k_rowsum<<<(NT + 3) / 4, 256, 0, stream>>>(supports, feature, ent_bank, labels,
                                               ent_new, yhat, class_v, class_thr,
                                               Wc, N, NT);
    k_colnorm<<<1, 256, 0, stream>>>(Wc, wn);
    k_out<<<cb, 256, 0, stream>>>(feature, wn, out, B);
}

// Round 2
// 547.024 us; speedup vs baseline: 2.4994x; 2.4994x over previous
//
#include <hip/hip_runtime.h>
#include <math.h>
#include <limits.h>

#define D 512
#define C 17
#define CAP 2048      // per-class selected-list capacity (= filter_K)
#define EQCAP 512     // per-class capacity for equal-to-threshold elements

// ---------------------------------------------------------------------------
// K1: logits -> entropy + argmax per batch row (unchanged from R1 — correct)
// ---------------------------------------------------------------------------
__global__ __launch_bounds__(256) void k_classify(
    const float* __restrict__ feature, const float* __restrict__ clf_w,
    const float* __restrict__ clf_b, float* __restrict__ ent_new,
    int* __restrict__ yhat, int B)
{
    __shared__ float w_s[C * D];
    __shared__ float b_s[C];
    int tid = threadIdx.x;
    for (int i = tid; i < C * D; i += 256) w_s[i] = clf_w[i];
    if (tid < C) b_s[tid] = clf_b[tid];
    __syncthreads();
    int wave = tid >> 6, lane = tid & 63;
    for (int row = blockIdx.x * 4 + wave; row < B; row += gridDim.x * 4) {
        const float* f = feature + (size_t)row * D;
        float4 f0 = *(const float4*)(f + lane * 8);
        float4 f1 = *(const float4*)(f + lane * 8 + 4);
        double p[C];
        for (int c = 0; c < C; ++c) {
            const float* w = w_s + c * D + lane * 8;
            double s = (double)f0.x * w[0] + (double)f0.y * w[1] +
                       (double)f0.z * w[2] + (double)f0.w * w[3] +
                       (double)f1.x * w[4] + (double)f1.y * w[5] +
                       (double)f1.z * w[6] + (double)f1.w * w[7];
            for (int m = 32; m; m >>= 1) s += __shfl_xor(s, m, 64);
            p[c] = s + (double)b_s[c];
        }
        if (lane == 0) {
            double mx = p[0]; int am = 0;
            for (int c = 1; c < C; ++c) if (p[c] > mx) { mx = p[c]; am = c; }
            double Z = 0.0, S = 0.0;
            for (int c = 0; c < C; ++c) {
                double e = exp(p[c] - mx);
                Z += e; S += e * (p[c] - mx);
            }
            double ent = log(Z) - S / Z;   // >= 0 always
            ent_new[row] = (float)ent;
            yhat[row] = am;
        }
    }
}

// ---------------------------------------------------------------------------
// grid-strided iteration over all NT concatenated elements, 4-wide vectorized
// f(index, label, entropy_bits)
// ---------------------------------------------------------------------------
template <typename F>
__device__ inline void for_all_g(int gtid, int gstride, int N, int NT,
    const float* __restrict__ eb, const int* __restrict__ lb,
    const float* __restrict__ en, const int* __restrict__ yh, F&& f)
{
    int nchunk = NT >> 2;
    for (int j = gtid; j < nchunk; j += gstride) {
        int base = j << 2;
        if (base + 4 <= N) {
            int4 y4 = *(const int4*)(lb + base);
            float4 e4 = *(const float4*)(eb + base);
            f(base + 0, y4.x, __float_as_uint(e4.x));
            f(base + 1, y4.y, __float_as_uint(e4.y));
            f(base + 2, y4.z, __float_as_uint(e4.z));
            f(base + 3, y4.w, __float_as_uint(e4.w));
        } else if (base >= N) {
            int4 y4 = *(const int4*)(yh + base - N);
            float4 e4 = *(const float4*)(en + base - N);
            f(base + 0, y4.x, __float_as_uint(e4.x));
            f(base + 1, y4.y, __float_as_uint(e4.y));
            f(base + 2, y4.z, __float_as_uint(e4.z));
            f(base + 3, y4.w, __float_as_uint(e4.w));
        } else {
            for (int k = 0; k < 4; ++k) {
                int i = base + k;
                int y = (i < N) ? lb[i] : yh[i - N];
                unsigned b = __float_as_uint((i < N) ? eb[i] : en[i - N]);
                f(i, y, b);
            }
        }
    }
    for (int i = (nchunk << 2) + gtid; i < NT; i += gstride) {
        int y = (i < N) ? lb[i] : yh[i - N];
        unsigned b = __float_as_uint((i < N) ? eb[i] : en[i - N]);
        f(i, y, b);
    }
}

// ---------------------------------------------------------------------------
// K2a (x4 levels): many-block per-class 256-bin histogram of one radix digit.
// ---------------------------------------------------------------------------
__global__ __launch_bounds__(256) void k_hist(
    const float* __restrict__ ent_bank, const int* __restrict__ labels,
    const float* __restrict__ ent_new, const int* __restrict__ yhat,
    unsigned* __restrict__ ghist, const unsigned* __restrict__ prefix,
    const int* __restrict__ done, int N, int B, int level)
{
    __shared__ unsigned h[C * 256];
    __shared__ unsigned pfx[C];
    __shared__ int dn[C];
    int tid = threadIdx.x;
    for (int i = tid; i < C * 256; i += 256) h[i] = 0;
    if (tid < C) { pfx[tid] = prefix[tid]; dn[tid] = done[tid]; }
    __syncthreads();
    int NT = N + B;
    int shift = 24 - 8 * level;
    for_all_g(blockIdx.x * 256 + tid, gridDim.x * 256, N, NT,
              ent_bank, labels, ent_new, yhat,
        [&](int i, int y, unsigned b) {
            (void)i;
            if (level > 0) {
                if (dn[y]) return;
                if ((b >> (shift + 8)) != pfx[y]) return;
            }
            atomicAdd(&h[y * 256 + ((b >> shift) & 255u)], 1u);
        });
    __syncthreads();
    for (int i = tid; i < C * 256; i += 256) {
        unsigned hv = h[i];
        if (hv) atomicAdd(&ghist[i], hv);
    }
}

// ---------------------------------------------------------------------------
// K2b (x4 levels): single tiny block — pick the bucket containing the K-th
// smallest per class, update prefix/krem, zero ghist for the next level.
// ---------------------------------------------------------------------------
__global__ __launch_bounds__(256) void k_pick(
    const int* __restrict__ fk, unsigned* __restrict__ ghist,
    unsigned* __restrict__ prefix, int* __restrict__ done,
    unsigned* __restrict__ v, int* __restrict__ thr,
    int* __restrict__ krem, int level)
{
    __shared__ unsigned h[256];
    __shared__ unsigned sc[256];
    __shared__ int s_b;
    __shared__ unsigned s_e;
    int tid = threadIdx.x;
    int K = fk[0];
    for (int c = 0; c < C; ++c) {
        if (level > 0 && done[c]) continue;      // uniform
        h[tid] = ghist[c * 256 + tid];
        ghist[c * 256 + tid] = 0;
        __syncthreads();
        sc[tid] = h[tid];
        __syncthreads();
        for (int off = 1; off < 256; off <<= 1) {
            unsigned x = sc[tid];
            if (tid >= off) x += sc[tid - off];
            __syncthreads();
            sc[tid] = x;
            __syncthreads();
        }
        if (level == 0 && (int)sc[255] <= K) {   // class has <= K members
            if (tid == 0) { done[c] = 1; v[c] = 0xFFFFFFFFu; thr[c] = INT_MAX; }
            __syncthreads();
            continue;
        }
        int Kin = (level == 0) ? K : krem[c];
        unsigned incl = sc[tid], excl = incl - h[tid];
        if ((int)excl < Kin && Kin <= (int)incl) { s_b = tid; s_e = excl; }
        __syncthreads();
        if (tid == 0) {
            unsigned p = (level == 0) ? (unsigned)s_b
                                      : ((prefix[c] << 8) | (unsigned)s_b);
            prefix[c] = p;
            krem[c] = Kin - (int)s_e;
            if (level == 3) v[c] = p;            // exact K-th smallest bits
        }
        __syncthreads();
    }
}

// ---------------------------------------------------------------------------
// K2c: collect indices whose entropy bits == v[c]  (for exact tie-break)
// ---------------------------------------------------------------------------
__global__ __launch_bounds__(256) void k_eq(
    const float* __restrict__ ent_bank, const int* __restrict__ labels,
    const float* __restrict__ ent_new, const int* __restrict__ yhat,
    const unsigned* __restrict__ v, const int* __restrict__ done,
    unsigned* __restrict__ eq_cnt, int* __restrict__ eq_idx, int N, int B)
{
    __shared__ unsigned vv[C];
    __shared__ int dn[C];
    int tid = threadIdx.x;
    if (tid < C) { vv[tid] = v[tid]; dn[tid] = done[tid]; }
    __syncthreads();
    for_all_g(blockIdx.x * 256 + tid, gridDim.x * 256, N, N + B,
              ent_bank, labels, ent_new, yhat,
        [&](int i, int y, unsigned b) {
            if (dn[y] || b != vv[y]) return;
            unsigned pos = atomicAdd(&eq_cnt[y], 1u);
            if (pos < EQCAP) eq_idx[y * EQCAP + pos] = i;
        });
}

// ---------------------------------------------------------------------------
// K2d: rank ties by index; thr[c] = Krem-th smallest index among ties
// ---------------------------------------------------------------------------
__global__ __launch_bounds__(256) void k_eqrank(
    const unsigned* __restrict__ eq_cnt, const int* __restrict__ eq_idx,
    const int* __restrict__ done, const int* __restrict__ krem,
    int* __restrict__ thr)
{
    int tid = threadIdx.x;
    for (int c = 0; c < C; ++c) {
        if (done[c]) continue;
        int n = (int)min(eq_cnt[c], (unsigned)EQCAP);
        int Kr = krem[c];
        for (int j = tid; j < n; j += 256) {
            int mine = eq_idx[c * EQCAP + j];
            int r = 0;
            for (int k = 0; k < n; ++k) r += (eq_idx[c * EQCAP + k] < mine);
            if (r == Kr - 1) thr[c] = mine;      // exactly one writer
        }
    }
}

// ---------------------------------------------------------------------------
// K3a: compact selected indices into per-class lists
// ---------------------------------------------------------------------------
__global__ __launch_bounds__(256) void k_compact(
    const float* __restrict__ ent_bank, const int* __restrict__ labels,
    const float* __restrict__ ent_new, const int* __restrict__ yhat,
    const unsigned* __restrict__ v, const int* __restrict__ thr,
    int* __restrict__ cnt, int* __restrict__ list, int N, int B)
{
    __shared__ unsigned vv[C];
    __shared__ int tt[C];
    int tid = threadIdx.x;
    if (tid < C) { vv[tid] = v[tid]; tt[tid] = thr[tid]; }
    __syncthreads();
    for_all_g(blockIdx.x * 256 + tid, gridDim.x * 256, N, N + B,
              ent_bank, labels, ent_new, yhat,
        [&](int i, int y, unsigned b) {
            unsigned V = vv[y];
            bool sel = (b < V) || (b == V && i <= tt[y]);
            if (!sel) return;
            int pos = atomicAdd(&cnt[y], 1);
            if (pos < CAP) list[y * CAP + pos] = i;
        });
}

// ---------------------------------------------------------------------------
// K3b: per-class sum of L2-normalized selected rows. grid = (chunks, C).
// Register accumulation -> LDS merge -> few global atomics (32/address).
// ---------------------------------------------------------------------------
__global__ __launch_bounds__(256) void k_accum(
    const float* __restrict__ supports, const float* __restrict__ feature,
    const int* __restrict__ list, const int* __restrict__ cnt,
    float* __restrict__ Wc, int N)
{
    int c = blockIdx.y;
    int s = min(cnt[c], CAP);
    int nch = gridDim.x;
    int R = (s + nch - 1) / nch;
    int start = blockIdx.x * R;
    int end = min(start + R, s);
    int lane = threadIdx.x & 63, wave = threadIdx.x >> 6;
    float a0 = 0.f, a1 = 0.f, a2 = 0.f, a3 = 0.f;
    float a4 = 0.f, a5 = 0.f, a6 = 0.f, a7 = 0.f;
    for (int j = start + wave; j < end; j += 4) {
        int r = list[c * CAP + j];
        const float* x = (r < N) ? (supports + (size_t)r * D)
                                 : (feature + (size_t)(r - N) * D);
        float4 p = *(const float4*)(x + lane * 8);
        float4 q = *(const float4*)(x + lane * 8 + 4);
        float ss = p.x * p.x + p.y * p.y + p.z * p.z + p.w * p.w +
                   q.x * q.x + q.y * q.y + q.z * q.z + q.w * q.w;
        for (int m = 32; m; m >>= 1) ss += __shfl_xor(ss, m, 64);
        float inv = 1.f / fmaxf(sqrtf(ss), 1e-12f);
        a0 += p.x * inv; a1 += p.y * inv; a2 += p.z * inv; a3 += p.w * inv;
        a4 += q.x * inv; a5 += q.y * inv; a6 += q.z * inv; a7 += q.w * inv;
    }
    __shared__ float wsum[4][D];
    *(float4*)&wsum[wave][lane * 8]     = make_float4(a0, a1, a2, a3);
    *(float4*)&wsum[wave][lane * 8 + 4] = make_float4(a4, a5, a6, a7);
    __syncthreads();
    for (int i = threadIdx.x; i < D; i += 256) {
        float t = wsum[0][i] + wsum[1][i] + wsum[2][i] + wsum[3][i];
        if (t != 0.f) atomicAdd(&Wc[c * D + i], t);
    }
}

// ---------------------------------------------------------------------------
// K5: out = feature @ (Wc^T column-normalized). Norms computed in-block.
// ---------------------------------------------------------------------------
__global__ __launch_bounds__(256) void k_out(
    const float* __restrict__ feature, const float* __restrict__ Wc,
    float* __restrict__ out, int B)
{
    __shared__ float w_s[C * D];
    __shared__ float inv_s[C];
    int tid = threadIdx.x;
    for (int i = tid; i < C * D; i += 256) w_s[i] = Wc[i];
    __syncthreads();
    int wave = tid >> 6, lane = tid & 63;
    for (int c = wave; c < C; c += 4) {
        const float* w = w_s + c * D + lane * 8;
        float ss = 0.f;
        for (int k = 0; k < 8; ++k) ss += w[k] * w[k];
        for (int m = 32; m; m >>= 1) ss += __shfl_xor(ss, m, 64);
        if (lane == 0) inv_s[c] = 1.f / fmaxf(sqrtf(ss), 1e-12f);
    }
    __syncthreads();
    for (int row = blockIdx.x * 4 + wave; row < B; row += gridDim.x * 4) {
        const float* f = feature + (size_t)row * D;
        float4 f0 = *(const float4*)(f + lane * 8);
        float4 f1 = *(const float4*)(f + lane * 8 + 4);
        for (int c = 0; c < C; ++c) {
            const float* w = w_s + c * D + lane * 8;
            float s = f0.x * w[0] + f0.y * w[1] + f0.z * w[2] + f0.w * w[3] +
                      f1.x * w[4] + f1.y * w[5] + f1.z * w[6] + f1.w * w[7];
            for (int m = 32; m; m >>= 1) s += __shfl_xor(s, m, 64);
            if (lane == 0) out[(size_t)row * C + c] = s * inv_s[c];
        }
    }
}

// ---------------------------------------------------------------------------
extern "C" void kernel_launch(void* const* d_in, const int* in_sizes, int n_in,
                              void* d_out, int out_size, void* d_ws, size_t ws_size,
                              hipStream_t stream)
{
    (void)n_in; (void)out_size; (void)ws_size;
    const float* feature  = (const float*)d_in[0];
    const float* clf_w    = (const float*)d_in[1];
    const float* clf_b    = (const float*)d_in[2];
    const float* supports = (const float*)d_in[3];
    const float* ent_bank = (const float*)d_in[4];
    const int*   labels   = (const int*)d_in[5];
    const int*   fk       = (const int*)d_in[6];
    int B  = in_sizes[0] / D;
    int N  = in_sizes[4];

    char* ws = (char*)d_ws;
    size_t o = 0;
    auto align256 = [&](size_t x) { return (x + 255) & ~(size_t)255; };
    // ---- zeroed region (one memset) ----
    float*    Wc      = (float*)(ws + o);    o = align256(o + (size_t)C * D * 4);
    unsigned* ghist   = (unsigned*)(ws + o); o = align256(o + (size_t)C * 256 * 4);
    int*      cnt     = (int*)(ws + o);      o = align256(o + 32 * 4);
    unsigned* eq_cnt  = (unsigned*)(ws + o); o = align256(o + 32 * 4);
    unsigned* prefix  = (unsigned*)(ws + o); o = align256(o + 32 * 4);
    int*      done    = (int*)(ws + o);      o = align256(o + 32 * 4);
    unsigned* v       = (unsigned*)(ws + o); o = align256(o + 32 * 4);
    int*      thr     = (int*)(ws + o);      o = align256(o + 32 * 4);
    int*      krem    = (int*)(ws + o);      o = align256(o + 32 * 4);
    size_t zero_bytes = o;
    // ---- non-zeroed region ----
    float*    ent_new = (float*)(ws + o);    o = align256(o + (size_t)B * 4);
    int*      yhat    = (int*)(ws + o);      o = align256(o + (size_t)B * 4);
    int*      eq_idx  = (int*)(ws + o);      o = align256(o + (size_t)C * EQCAP * 4);
    int*      list    = (int*)(ws + o);      o = align256(o + (size_t)C * CAP * 4);
    float*    out     = (float*)d_out;

    hipMemsetAsync(ws, 0, zero_bytes, stream);

    int cb = (B + 3) / 4; if (cb > 1024) cb = 1024;
    const int SG = 128;   // scan grid

    k_classify<<<cb, 256, 0, stream>>>(feature, clf_w, clf_b, ent_new, yhat, B);
    for (int level = 0; level < 4; ++level) {
        k_hist<<<SG, 256, 0, stream>>>(ent_bank, labels, ent_new, yhat,
                                       ghist, prefix, done, N, B, level);
        k_pick<<<1, 256, 0, stream>>>(fk, ghist, prefix, done, v, thr, krem, level);
    }
    k_eq<<<SG, 256, 0, stream>>>(ent_bank, labels, ent_new, yhat,
                                 v, done, eq_cnt, eq_idx, N, B);
    k_eqrank<<<1, 256, 0, stream>>>(eq_cnt, eq_idx, done, krem, thr);
    k_compact<<<SG, 256, 0, stream>>>(ent_bank, labels, ent_new, yhat,
                                      v, thr, cnt, list, N, B);
    k_accum<<<dim3(32, C), 256, 0, stream>>>(supports, feature, list, cnt, Wc, N);
    k_out<<<cb, 256, 0, stream>>>(feature, Wc, out, B);
}

// Round 3
// 458.540 us; speedup vs baseline: 2.9818x; 1.1930x over previous
//
#include <hip/hip_runtime.h>
#include <math.h>
#include <limits.h>

#define D 512
#define C 17
#define CAP 2048      // per-class selected-list capacity (= filter_K)
#define CANDCAP 2048  // per-class boundary-bucket candidate capacity

// ---------------------------------------------------------------------------
// K1: logits -> entropy + argmax per batch row (double precision for exact
// ordering at the selection boundary; verified R1/R2)
// ---------------------------------------------------------------------------
__global__ __launch_bounds__(256) void k_classify(
    const float* __restrict__ feature, const float* __restrict__ clf_w,
    const float* __restrict__ clf_b, float* __restrict__ ent_new,
    int* __restrict__ yhat, int B)
{
    __shared__ float w_s[C * D];
    __shared__ float b_s[C];
    int tid = threadIdx.x;
    for (int i = tid; i < C * D; i += 256) w_s[i] = clf_w[i];
    if (tid < C) b_s[tid] = clf_b[tid];
    __syncthreads();
    int wave = tid >> 6, lane = tid & 63;
    for (int row = blockIdx.x * 4 + wave; row < B; row += gridDim.x * 4) {
        const float* f = feature + (size_t)row * D;
        float4 f0 = *(const float4*)(f + lane * 8);
        float4 f1 = *(const float4*)(f + lane * 8 + 4);
        double p[C];
        for (int c = 0; c < C; ++c) {
            const float* w = w_s + c * D + lane * 8;
            double s = (double)f0.x * w[0] + (double)f0.y * w[1] +
                       (double)f0.z * w[2] + (double)f0.w * w[3] +
                       (double)f1.x * w[4] + (double)f1.y * w[5] +
                       (double)f1.z * w[6] + (double)f1.w * w[7];
            for (int m = 32; m; m >>= 1) s += __shfl_xor(s, m, 64);
            p[c] = s + (double)b_s[c];
        }
        if (lane == 0) {
            double mx = p[0]; int am = 0;
            for (int c = 1; c < C; ++c) if (p[c] > mx) { mx = p[c]; am = c; }
            double Z = 0.0, S = 0.0;
            for (int c = 0; c < C; ++c) {
                double e = exp(p[c] - mx);
                Z += e; S += e * (p[c] - mx);
            }
            double ent = log(Z) - S / Z;   // >= 0 always
            ent_new[row] = (float)ent;
            yhat[row] = am;
        }
    }
}

// ---------------------------------------------------------------------------
// grid-strided iteration over all NT concatenated elements, 4-wide vectorized
// f(index, label, entropy_bits)
// ---------------------------------------------------------------------------
template <typename F>
__device__ inline void for_all_g(int gtid, int gstride, int N, int NT,
    const float* __restrict__ eb, const int* __restrict__ lb,
    const float* __restrict__ en, const int* __restrict__ yh, F&& f)
{
    int nchunk = NT >> 2;
    for (int j = gtid; j < nchunk; j += gstride) {
        int base = j << 2;
        if (base + 4 <= N) {
            int4 y4 = *(const int4*)(lb + base);
            float4 e4 = *(const float4*)(eb + base);
            f(base + 0, y4.x, __float_as_uint(e4.x));
            f(base + 1, y4.y, __float_as_uint(e4.y));
            f(base + 2, y4.z, __float_as_uint(e4.z));
            f(base + 3, y4.w, __float_as_uint(e4.w));
        } else if (base >= N) {
            int4 y4 = *(const int4*)(yh + base - N);
            float4 e4 = *(const float4*)(en + base - N);
            f(base + 0, y4.x, __float_as_uint(e4.x));
            f(base + 1, y4.y, __float_as_uint(e4.y));
            f(base + 2, y4.z, __float_as_uint(e4.z));
            f(base + 3, y4.w, __float_as_uint(e4.w));
        } else {
            for (int k = 0; k < 4; ++k) {
                int i = base + k;
                int y = (i < N) ? lb[i] : yh[i - N];
                unsigned b = __float_as_uint((i < N) ? eb[i] : en[i - N]);
                f(i, y, b);
            }
        }
    }
    for (int i = (nchunk << 2) + gtid; i < NT; i += gstride) {
        int y = (i < N) ? lb[i] : yh[i - N];
        unsigned b = __float_as_uint((i < N) ? eb[i] : en[i - N]);
        f(i, y, b);
    }
}

// ---------------------------------------------------------------------------
// K2: one pass -> per-class 16-bit global histogram (top 16 bits of float)
//     + per-class 8-bit chunk histogram (LDS, merged to global)
// ---------------------------------------------------------------------------
__global__ __launch_bounds__(256) void k_hist16(
    const float* __restrict__ ent_bank, const int* __restrict__ labels,
    const float* __restrict__ ent_new, const int* __restrict__ yhat,
    unsigned* __restrict__ hist16, unsigned* __restrict__ ghist8,
    int N, int B)
{
    __shared__ unsigned h8[C * 256];
    int tid = threadIdx.x;
    for (int i = tid; i < C * 256; i += 256) h8[i] = 0;
    __syncthreads();
    for_all_g(blockIdx.x * 256 + tid, gridDim.x * 256, N, N + B,
              ent_bank, labels, ent_new, yhat,
        [&](int i, int y, unsigned b) {
            (void)i;
            atomicAdd(&hist16[(size_t)y * 65536 + (b >> 16)], 1u);
            atomicAdd(&h8[y * 256 + (b >> 24)], 1u);
        });
    __syncthreads();
    for (int i = tid; i < C * 256; i += 256) {
        unsigned v = h8[i];
        if (v) atomicAdd(&ghist8[i], v);
    }
}

// ---------------------------------------------------------------------------
// in-wave helper: given 4 bins/lane (h[0..3]) find the bin where the running
// cumulative count crosses rank K. Returns (bin, excl_before_bin) broadcast
// to all lanes.
// ---------------------------------------------------------------------------
__device__ inline void wave_rank256(const unsigned h[4], int K, int lane,
                                    int* out_bin, int* out_excl, unsigned* out_total)
{
    unsigned lsum = h[0] + h[1] + h[2] + h[3];
    unsigned x = lsum;
    for (int off = 1; off < 64; off <<= 1) {
        unsigned t = __shfl_up(x, off, 64);
        if (lane >= off) x += t;
    }
    *out_total = __shfl((int)x, 63, 64);
    unsigned excl = x - lsum;
    int myb = -1; int mye = 0;
    unsigned run = excl;
    for (int k = 0; k < 4; ++k) {
        unsigned inc = run + h[k];
        if ((int)run < K && K <= (int)inc) { myb = lane * 4 + k; mye = (int)run; }
        run = inc;
    }
    unsigned long long m = __ballot(myb >= 0);
    int src = (int)__ffsll((unsigned long long)m) - 1;
    *out_bin  = __shfl(myb, src, 64);
    *out_excl = __shfl(mye, src, 64);
}

// ---------------------------------------------------------------------------
// K3: wave-parallel pick — classes across waves, pure in-wave shuffle scans.
// Output: prefix16[c] (16-bit bucket of the K-th smallest), krem[c], done[c].
// ---------------------------------------------------------------------------
__global__ __launch_bounds__(256) void k_pick(
    const int* __restrict__ fk, const unsigned* __restrict__ ghist8,
    const unsigned* __restrict__ hist16, unsigned* __restrict__ prefix16,
    int* __restrict__ krem, int* __restrict__ done)
{
    int wave = threadIdx.x >> 6, lane = threadIdx.x & 63;
    int K = fk[0];
    for (int c = wave; c < C; c += 4) {
        unsigned h[4];
        const unsigned* g = ghist8 + c * 256 + lane * 4;
        h[0] = g[0]; h[1] = g[1]; h[2] = g[2]; h[3] = g[3];
        int chunk, e1; unsigned total;
        wave_rank256(h, K, lane, &chunk, &e1, &total);
        if ((int)total <= K) {              // class has <= K members: take all
            if (lane == 0) done[c] = 1;
            continue;
        }
        int K2 = K - e1;
        const unsigned* g2 = hist16 + (size_t)c * 65536 + chunk * 256 + lane * 4;
        unsigned h2[4];
        h2[0] = g2[0]; h2[1] = g2[1]; h2[2] = g2[2]; h2[3] = g2[3];
        int bin, e2; unsigned tot2;
        wave_rank256(h2, K2, lane, &bin, &e2, &tot2);
        if (lane == 0) {
            done[c] = 0;
            prefix16[c] = (unsigned)(chunk * 256 + bin);
            krem[c] = K2 - e2;              // still needed inside boundary bucket
        }
    }
}

// ---------------------------------------------------------------------------
// K4: compact — definite selections (bucket < boundary, or done-class) into
// list[]; boundary-bucket elements into candidate arrays for exact tie-break.
// ---------------------------------------------------------------------------
__global__ __launch_bounds__(256) void k_compact(
    const float* __restrict__ ent_bank, const int* __restrict__ labels,
    const float* __restrict__ ent_new, const int* __restrict__ yhat,
    const unsigned* __restrict__ prefix16, const int* __restrict__ done,
    int* __restrict__ cnt, int* __restrict__ list,
    unsigned* __restrict__ ccnt, unsigned* __restrict__ candb,
    int* __restrict__ candi, int N, int B)
{
    __shared__ unsigned p[C];
    __shared__ int dn[C];
    int tid = threadIdx.x;
    if (tid < C) { p[tid] = prefix16[tid]; dn[tid] = done[tid]; }
    __syncthreads();
    for_all_g(blockIdx.x * 256 + tid, gridDim.x * 256, N, N + B,
              ent_bank, labels, ent_new, yhat,
        [&](int i, int y, unsigned b) {
            unsigned t16 = b >> 16;
            if (dn[y] || t16 < p[y]) {
                int pos = atomicAdd(&cnt[y], 1);
                if (pos < CAP) list[y * CAP + pos] = i;
            } else if (t16 == p[y]) {
                unsigned pos = atomicAdd(&ccnt[y], 1u);
                if (pos < CANDCAP) {
                    candb[y * CANDCAP + pos] = b;
                    candi[y * CANDCAP + pos] = i;
                }
            }
        });
}

// ---------------------------------------------------------------------------
// K5: finish — exact (bits, index)-lexicographic rank among boundary
// candidates; append the krem winners; publish final count scnt[c].
// Matches jax.lax.top_k tie-break (lowest index first) bit-exactly.
// ---------------------------------------------------------------------------
__global__ __launch_bounds__(256) void k_finish(
    const unsigned* __restrict__ ccnt, const unsigned* __restrict__ candb,
    const int* __restrict__ candi, const int* __restrict__ done,
    const int* __restrict__ krem, const int* __restrict__ cnt,
    int* __restrict__ list, int* __restrict__ scnt)
{
    __shared__ unsigned sb[4][1024];
    __shared__ int si[4][1024];
    int wave = threadIdx.x >> 6, lane = threadIdx.x & 63;
    for (int c = wave; c < C; c += 4) {
        if (done[c]) {
            if (lane == 0) scnt[c] = min(cnt[c], CAP);
            continue;
        }
        int n = (int)min(ccnt[c], (unsigned)CANDCAP);
        int Kr = krem[c];
        int base = cnt[c];
        if (n <= 1024) {
            for (int j = lane; j < n; j += 64) {
                sb[wave][j] = candb[c * CANDCAP + j];
                si[wave][j] = candi[c * CANDCAP + j];
            }
            // wave64 lockstep: same-wave LDS write->read is ordered
            for (int j = lane; j < n; j += 64) {
                unsigned bj = sb[wave][j]; int ij = si[wave][j];
                int r = 0;
                for (int k = 0; k < n; ++k) {
                    unsigned bk = sb[wave][k]; int ik = si[wave][k];
                    r += (bk < bj || (bk == bj && ik < ij)) ? 1 : 0;
                }
                if (r < Kr && base + r < CAP) list[c * CAP + base + r] = ij;
            }
        } else {   // overflow fallback (never hit with this data)
            for (int j = lane; j < n; j += 64) {
                unsigned bj = candb[c * CANDCAP + j]; int ij = candi[c * CANDCAP + j];
                int r = 0;
                for (int k = 0; k < n; ++k) {
                    unsigned bk = candb[c * CANDCAP + k]; int ik = candi[c * CANDCAP + k];
                    r += (bk < bj || (bk == bj && ik < ij)) ? 1 : 0;
                }
                if (r < Kr && base + r < CAP) list[c * CAP + base + r] = ij;
            }
        }
        if (lane == 0) scnt[c] = min(base + min(Kr, n), CAP);
    }
}

// ---------------------------------------------------------------------------
// K6: per-class sum of L2-normalized selected rows. grid = (32 chunks, C).
// Register accumulation -> LDS merge -> 512 global atomics per block.
// ---------------------------------------------------------------------------
__global__ __launch_bounds__(256) void k_accum(
    const float* __restrict__ supports, const float* __restrict__ feature,
    const int* __restrict__ list, const int* __restrict__ scnt,
    float* __restrict__ Wc, int N)
{
    int c = blockIdx.y;
    int s = min(scnt[c], CAP);
    int nch = gridDim.x;
    int R = (s + nch - 1) / nch;
    int start = blockIdx.x * R;
    int end = min(start + R, s);
    int lane = threadIdx.x & 63, wave = threadIdx.x >> 6;
    float a0 = 0.f, a1 = 0.f, a2 = 0.f, a3 = 0.f;
    float a4 = 0.f, a5 = 0.f, a6 = 0.f, a7 = 0.f;
    for (int j = start + wave; j < end; j += 4) {
        int r = list[c * CAP + j];
        const float* x = (r < N) ? (supports + (size_t)r * D)
                                 : (feature + (size_t)(r - N) * D);
        float4 p = *(const float4*)(x + lane * 8);
        float4 q = *(const float4*)(x + lane * 8 + 4);
        float ss = p.x * p.x + p.y * p.y + p.z * p.z + p.w * p.w +
                   q.x * q.x + q.y * q.y + q.z * q.z + q.w * q.w;
        for (int m = 32; m; m >>= 1) ss += __shfl_xor(ss, m, 64);
        float inv = 1.f / fmaxf(sqrtf(ss), 1e-12f);
        a0 += p.x * inv; a1 += p.y * inv; a2 += p.z * inv; a3 += p.w * inv;
        a4 += q.x * inv; a5 += q.y * inv; a6 += q.z * inv; a7 += q.w * inv;
    }
    __shared__ float wsum[4][D];
    *(float4*)&wsum[wave][lane * 8]     = make_float4(a0, a1, a2, a3);
    *(float4*)&wsum[wave][lane * 8 + 4] = make_float4(a4, a5, a6, a7);
    __syncthreads();
    for (int i = threadIdx.x; i < D; i += 256) {
        float t = wsum[0][i] + wsum[1][i] + wsum[2][i] + wsum[3][i];
        if (t != 0.f) atomicAdd(&Wc[c * D + i], t);
    }
}

// ---------------------------------------------------------------------------
// K7: out = feature @ (Wc^T column-normalized). Norms computed in-block.
// ---------------------------------------------------------------------------
__global__ __launch_bounds__(256) void k_out(
    const float* __restrict__ feature, const float* __restrict__ Wc,
    float* __restrict__ out, int B)
{
    __shared__ float w_s[C * D];
    __shared__ float inv_s[C];
    int tid = threadIdx.x;
    for (int i = tid; i < C * D; i += 256) w_s[i] = Wc[i];
    __syncthreads();
    int wave = tid >> 6, lane = tid & 63;
    for (int c = wave; c < C; c += 4) {
        const float* w = w_s + c * D + lane * 8;
        float ss = 0.f;
        for (int k = 0; k < 8; ++k) ss += w[k] * w[k];
        for (int m = 32; m; m >>= 1) ss += __shfl_xor(ss, m, 64);
        if (lane == 0) inv_s[c] = 1.f / fmaxf(sqrtf(ss), 1e-12f);
    }
    __syncthreads();
    for (int row = blockIdx.x * 4 + wave; row < B; row += gridDim.x * 4) {
        const float* f = feature + (size_t)row * D;
        float4 f0 = *(const float4*)(f + lane * 8);
        float4 f1 = *(const float4*)(f + lane * 8 + 4);
        for (int c = 0; c < C; ++c) {
            const float* w = w_s + c * D + lane * 8;
            float s = f0.x * w[0] + f0.y * w[1] + f0.z * w[2] + f0.w * w[3] +
                      f1.x * w[4] + f1.y * w[5] + f1.z * w[6] + f1.w * w[7];
            for (int m = 32; m; m >>= 1) s += __shfl_xor(s, m, 64);
            if (lane == 0) out[(size_t)row * C + c] = s * inv_s[c];
        }
    }
}

// ---------------------------------------------------------------------------
extern "C" void kernel_launch(void* const* d_in, const int* in_sizes, int n_in,
                              void* d_out, int out_size, void* d_ws, size_t ws_size,
                              hipStream_t stream)
{
    (void)n_in; (void)out_size; (void)ws_size;
    const float* feature  = (const float*)d_in[0];
    const float* clf_w    = (const float*)d_in[1];
    const float* clf_b    = (const float*)d_in[2];
    const float* supports = (const float*)d_in[3];
    const float* ent_bank = (const float*)d_in[4];
    const int*   labels   = (const int*)d_in[5];
    const int*   fk       = (const int*)d_in[6];
    int B  = in_sizes[0] / D;
    int N  = in_sizes[4];

    char* ws = (char*)d_ws;
    size_t o = 0;
    auto align256 = [&](size_t x) { return (x + 255) & ~(size_t)255; };
    // ---- zeroed region (one memset) ----
    unsigned* hist16  = (unsigned*)(ws + o); o = align256(o + (size_t)C * 65536 * 4);
    unsigned* ghist8  = (unsigned*)(ws + o); o = align256(o + (size_t)C * 256 * 4);
    float*    Wc      = (float*)(ws + o);    o = align256(o + (size_t)C * D * 4);
    int*      cnt     = (int*)(ws + o);      o = align256(o + 32 * 4);
    unsigned* ccnt    = (unsigned*)(ws + o); o = align256(o + 32 * 4);
    size_t zero_bytes = o;
    // ---- non-zeroed region (always fully written before read) ----
    float*    ent_new = (float*)(ws + o);    o = align256(o + (size_t)B * 4);
    int*      yhat    = (int*)(ws + o);      o = align256(o + (size_t)B * 4);
    unsigned* prefix16= (unsigned*)(ws + o); o = align256(o + 32 * 4);
    int*      krem    = (int*)(ws + o);      o = align256(o + 32 * 4);
    int*      done    = (int*)(ws + o);      o = align256(o + 32 * 4);
    int*      scnt    = (int*)(ws + o);      o = align256(o + 32 * 4);
    int*      list    = (int*)(ws + o);      o = align256(o + (size_t)C * CAP * 4);
    unsigned* candb   = (unsigned*)(ws + o); o = align256(o + (size_t)C * CANDCAP * 4);
    int*      candi   = (int*)(ws + o);      o = align256(o + (size_t)C * CANDCAP * 4);
    float*    out     = (float*)d_out;

    hipMemsetAsync(ws, 0, zero_bytes, stream);

    int cb = (B + 3) / 4; if (cb > 1024) cb = 1024;
    const int SG = 256;   // scan grid

    k_classify<<<cb, 256, 0, stream>>>(feature, clf_w, clf_b, ent_new, yhat, B);
    k_hist16<<<SG, 256, 0, stream>>>(ent_bank, labels, ent_new, yhat,
                                     hist16, ghist8, N, B);
    k_pick<<<1, 256, 0, stream>>>(fk, ghist8, hist16, prefix16, krem, done);
    k_compact<<<SG, 256, 0, stream>>>(ent_bank, labels, ent_new, yhat,
                                      prefix16, done, cnt, list,
                                      ccnt, candb, candi, N, B);
    k_finish<<<1, 256, 0, stream>>>(ccnt, candb, candi, done, krem, cnt,
                                    list, scnt);
    k_accum<<<dim3(32, C), 256, 0, stream>>>(supports, feature, list, scnt, Wc, N);
    k_out<<<cb, 256, 0, stream>>>(feature, Wc, out, B);
}

// Round 4
// 359.351 us; speedup vs baseline: 3.8048x; 1.2760x over previous
//
#include <hip/hip_runtime.h>
#include <math.h>
#include <limits.h>

#define D 512
#define C 17
#define CAP 2048      // per-class selected-list capacity (= filter_K)
#define CANDCAP 2048  // per-class boundary-bucket candidate capacity
#define PAD 64        // counter padding stride (ints) -> 256 B apart

// ---------------------------------------------------------------------------
// K1 "front": classify batch rows (entropy+argmax, fp64 interior) AND build
// per-class histograms (16-bit fine + 8-bit coarse) over bank+batch.
// ---------------------------------------------------------------------------
__global__ __launch_bounds__(256) void k_front(
    const float* __restrict__ feature, const float* __restrict__ clf_w,
    const float* __restrict__ clf_b, const float* __restrict__ ent_bank,
    const int* __restrict__ labels, float* __restrict__ ent_new,
    int* __restrict__ yhat, unsigned* __restrict__ hist16,
    unsigned* __restrict__ ghist8, int N, int B)
{
    __shared__ float w_s[C * D];
    __shared__ float b_s[C];
    int tid = threadIdx.x;
    for (int i = tid; i < C * D; i += 256) w_s[i] = clf_w[i];
    if (tid < C) b_s[tid] = clf_b[tid];
    __syncthreads();
    int wave = tid >> 6, lane = tid & 63;

    // ---- classify: one batch row per wave ----
    int row = blockIdx.x * 4 + wave;
    if (row < B) {
        const float* f = feature + (size_t)row * D;
        float4 f0 = *(const float4*)(f + lane * 8);
        float4 f1 = *(const float4*)(f + lane * 8 + 4);
        double p[C];
        for (int c = 0; c < C; ++c) {
            const float* w = w_s + c * D + lane * 8;
            double s = (double)f0.x * w[0] + (double)f0.y * w[1] +
                       (double)f0.z * w[2] + (double)f0.w * w[3] +
                       (double)f1.x * w[4] + (double)f1.y * w[5] +
                       (double)f1.z * w[6] + (double)f1.w * w[7];
            for (int m = 32; m; m >>= 1) s += __shfl_xor(s, m, 64);
            p[c] = s + (double)b_s[c];
        }
        if (lane == 0) {
            double mx = p[0]; int am = 0;
            for (int c = 1; c < C; ++c) if (p[c] > mx) { mx = p[c]; am = c; }
            double Z = 0.0, S = 0.0;
            for (int c = 0; c < C; ++c) {
                double e = exp(p[c] - mx);
                Z += e; S += e * (p[c] - mx);
            }
            float ent = (float)(log(Z) - S / Z);   // >= 0 always
            ent_new[row] = ent;
            yhat[row] = am;
            unsigned b = __float_as_uint(ent);
            atomicAdd(&hist16[(size_t)am * 65536 + (b >> 16)], 1u);
            atomicAdd(&ghist8[am * 256 + (b >> 24)], 1u);
        }
    }

    // ---- bank histogram: one 4-chunk per thread (grid covers N/4) ----
    int gtid = blockIdx.x * 256 + tid;
    int nchunk = N >> 2;
    if (gtid < nchunk) {
        int4 y4 = *(const int4*)(labels + gtid * 4);
        float4 e4 = *(const float4*)(ent_bank + gtid * 4);
        unsigned b;
        b = __float_as_uint(e4.x);
        atomicAdd(&hist16[(size_t)y4.x * 65536 + (b >> 16)], 1u);
        atomicAdd(&ghist8[y4.x * 256 + (b >> 24)], 1u);
        b = __float_as_uint(e4.y);
        atomicAdd(&hist16[(size_t)y4.y * 65536 + (b >> 16)], 1u);
        atomicAdd(&ghist8[y4.y * 256 + (b >> 24)], 1u);
        b = __float_as_uint(e4.z);
        atomicAdd(&hist16[(size_t)y4.z * 65536 + (b >> 16)], 1u);
        atomicAdd(&ghist8[y4.z * 256 + (b >> 24)], 1u);
        b = __float_as_uint(e4.w);
        atomicAdd(&hist16[(size_t)y4.w * 65536 + (b >> 16)], 1u);
        atomicAdd(&ghist8[y4.w * 256 + (b >> 24)], 1u);
    }
    // bank tail (N % 4), handled by block 0
    if (blockIdx.x == 0) {
        for (int i = (nchunk << 2) + tid; i < N; i += 256) {
            int y = labels[i];
            unsigned b = __float_as_uint(ent_bank[i]);
            atomicAdd(&hist16[(size_t)y * 65536 + (b >> 16)], 1u);
            atomicAdd(&ghist8[y * 256 + (b >> 24)], 1u);
        }
    }
}

// ---------------------------------------------------------------------------
// in-wave helper: given 4 bins/lane (h[0..3]) find the bin where the running
// cumulative count crosses rank K. Broadcasts (bin, excl, total).
// ---------------------------------------------------------------------------
__device__ inline void wave_rank256(const unsigned h[4], int K, int lane,
                                    int* out_bin, int* out_excl, unsigned* out_total)
{
    unsigned lsum = h[0] + h[1] + h[2] + h[3];
    unsigned x = lsum;
    for (int off = 1; off < 64; off <<= 1) {
        unsigned t = __shfl_up(x, off, 64);
        if (lane >= off) x += t;
    }
    *out_total = __shfl((int)x, 63, 64);
    unsigned excl = x - lsum;
    int myb = -1; int mye = 0;
    unsigned run = excl;
    for (int k = 0; k < 4; ++k) {
        unsigned inc = run + h[k];
        if ((int)run < K && K <= (int)inc) { myb = lane * 4 + k; mye = (int)run; }
        run = inc;
    }
    unsigned long long m = __ballot(myb >= 0);
    int src = (int)__ffsll((unsigned long long)m) - 1;
    *out_bin  = __shfl(myb, src, 64);
    *out_excl = __shfl(mye, src, 64);
}

// ---------------------------------------------------------------------------
// K2 "compact": per-block redundant pick (from ghist8 + one hist16 row per
// class), then scan all NT elements; definite selections compacted in LDS
// and flushed with ONE padded global atomic per class per block; boundary-
// bucket elements go to candidate arrays (rare, direct atomics).
// Block 0 persists krem[] for k_accum's tie-break finish.
// ---------------------------------------------------------------------------
__global__ __launch_bounds__(256) void k_compact(
    const float* __restrict__ ent_bank, const int* __restrict__ labels,
    const float* __restrict__ ent_new, const int* __restrict__ yhat,
    const unsigned* __restrict__ ghist8, const unsigned* __restrict__ hist16,
    const int* __restrict__ fk, int* __restrict__ krem_g,
    int* __restrict__ cnt_g, int* __restrict__ list,
    unsigned* __restrict__ ccnt_g, unsigned* __restrict__ candb,
    int* __restrict__ candi, int N, int B)
{
    __shared__ unsigned pfx16[C];
    __shared__ int krem_s[C];
    __shared__ int done_s[C];
    __shared__ int lcnt[C], lofs[C], lput[C], gbase[C];
    __shared__ int l_list[1024 + 8];

    int tid = threadIdx.x, wave = tid >> 6, lane = tid & 63;
    int K = fk[0];

    // ---- pick (redundant per block, wave-parallel over classes) ----
    for (int c = wave; c < C; c += 4) {
        uint4 g0 = *(const uint4*)(ghist8 + c * 256 + lane * 4);
        unsigned h[4] = { g0.x, g0.y, g0.z, g0.w };
        int chunk, e1; unsigned total;
        wave_rank256(h, K, lane, &chunk, &e1, &total);
        if ((int)total <= K) {
            if (lane == 0) { done_s[c] = 1; krem_s[c] = 0; pfx16[c] = 0xFFFFFFFFu; }
            continue;
        }
        int K2 = K - e1;
        uint4 g1 = *(const uint4*)(hist16 + (size_t)c * 65536 + chunk * 256 + lane * 4);
        unsigned h2[4] = { g1.x, g1.y, g1.z, g1.w };
        int bin, e2; unsigned tot2;
        wave_rank256(h2, K2, lane, &bin, &e2, &tot2);
        if (lane == 0) {
            done_s[c] = 0;
            pfx16[c] = (unsigned)(chunk * 256 + bin);
            krem_s[c] = K2 - e2;
        }
    }
    if (tid < C) { lcnt[tid] = 0; }
    __syncthreads();
    if (blockIdx.x == 0 && tid < C) krem_g[tid] = krem_s[tid];

    // ---- load this thread's elements (<= 1 four-chunk + rare tail) ----
    int NT = N + B;
    int nchunk = NT >> 2;
    int gtid = blockIdx.x * 256 + tid;
    int4 y4; uint4 b4; int i0 = gtid << 2; int vn = 0;
    if (gtid < nchunk) {
        vn = 4;
        if (i0 + 4 <= N) {
            y4 = *(const int4*)(labels + i0);
            float4 e = *(const float4*)(ent_bank + i0);
            b4 = make_uint4(__float_as_uint(e.x), __float_as_uint(e.y),
                            __float_as_uint(e.z), __float_as_uint(e.w));
        } else if (i0 >= N) {
            y4 = *(const int4*)(yhat + (i0 - N));
            float4 e = *(const float4*)(ent_new + (i0 - N));
            b4 = make_uint4(__float_as_uint(e.x), __float_as_uint(e.y),
                            __float_as_uint(e.z), __float_as_uint(e.w));
        } else {   // straddle (only if N % 4 != 0)
            int ys[4]; unsigned bs[4];
            for (int k = 0; k < 4; ++k) {
                int i = i0 + k;
                ys[k] = (i < N) ? labels[i] : yhat[i - N];
                bs[k] = __float_as_uint((i < N) ? ent_bank[i] : ent_new[i - N]);
            }
            y4 = make_int4(ys[0], ys[1], ys[2], ys[3]);
            b4 = make_uint4(bs[0], bs[1], bs[2], bs[3]);
        }
    }
    int y_t = 0; unsigned b_t = 0; int i_t = 0; int have_t = 0;
    int tail0 = nchunk << 2;
    if (blockIdx.x == 0 && tail0 + tid < NT) {
        i_t = tail0 + tid;
        y_t = (i_t < N) ? labels[i_t] : yhat[i_t - N];
        b_t = __float_as_uint((i_t < N) ? ent_bank[i_t] : ent_new[i_t - N]);
        have_t = 1;
    }

    auto each = [&](auto&& g) {
        if (vn > 0) { g(y4.x, b4.x, i0 + 0); g(y4.y, b4.y, i0 + 1);
                      g(y4.z, b4.z, i0 + 2); g(y4.w, b4.w, i0 + 3); }
        if (have_t) g(y_t, b_t, i_t);
    };

    // ---- pass A: count selected per class ----
    each([&](int y, unsigned b, int i) {
        (void)i;
        unsigned t16 = b >> 16;
        if (done_s[y] || t16 < pfx16[y]) atomicAdd(&lcnt[y], 1);
    });
    __syncthreads();
    // ---- scan + reserve global ranges (17 padded atomics per block) ----
    if (tid == 0) {
        int run = 0;
        for (int c = 0; c < C; ++c) { lofs[c] = run; run += lcnt[c]; }
    }
    __syncthreads();
    if (tid < C) {
        gbase[tid] = atomicAdd(&cnt_g[tid * PAD], lcnt[tid]);
        lput[tid] = lofs[tid];
    }
    __syncthreads();
    // ---- pass B: scatter into LDS; candidates direct to global ----
    each([&](int y, unsigned b, int i) {
        unsigned t16 = b >> 16;
        if (done_s[y] || t16 < pfx16[y]) {
            int p = atomicAdd(&lput[y], 1);
            l_list[p] = i;
        } else if (t16 == pfx16[y]) {
            unsigned q = atomicAdd(&ccnt_g[y * PAD], 1u);
            if (q < CANDCAP) { candb[y * CANDCAP + q] = b; candi[y * CANDCAP + q] = i; }
        }
    });
    __syncthreads();
    // ---- pass C: bulk coalesced copy LDS -> global list ----
    for (int c = 0; c < C; ++c) {
        int m = lcnt[c], base = gbase[c], off = lofs[c];
        for (int t = tid; t < m; t += 256)
            list[c * CAP + base + t] = l_list[off + t];
    }
}

// ---------------------------------------------------------------------------
// K3 "accum": per-class sum of L2-normalized selected rows. grid=(32, C).
// Block x==0 additionally ranks boundary candidates by exact (bits,index)
// order (jax.lax.top_k tie-break) and accumulates the krem winners.
// ---------------------------------------------------------------------------
__global__ __launch_bounds__(256) void k_accum(
    const float* __restrict__ supports, const float* __restrict__ feature,
    const int* __restrict__ list, const int* __restrict__ cnt_g,
    const unsigned* __restrict__ ccnt_g, const unsigned* __restrict__ candb,
    const int* __restrict__ candi, const int* __restrict__ krem_g,
    float* __restrict__ Wc, int N)
{
    __shared__ float wsum[4][D];
    __shared__ unsigned cb_s[CANDCAP];
    __shared__ int ci_s[CANDCAP];
    __shared__ int win[CANDCAP];
    __shared__ int wn_s;

    int c = blockIdx.y;
    int s = min(cnt_g[c * PAD], CAP);
    int nch = gridDim.x;
    int R = (s + nch - 1) / nch;
    int start = blockIdx.x * R;
    int end = min(start + R, s);
    int lane = threadIdx.x & 63, wave = threadIdx.x >> 6;
    float a0 = 0.f, a1 = 0.f, a2 = 0.f, a3 = 0.f;
    float a4 = 0.f, a5 = 0.f, a6 = 0.f, a7 = 0.f;

    auto add_row = [&](int r) {
        const float* x = (r < N) ? (supports + (size_t)r * D)
                                 : (feature + (size_t)(r - N) * D);
        float4 p = *(const float4*)(x + lane * 8);
        float4 q = *(const float4*)(x + lane * 8 + 4);
        float ss = p.x * p.x + p.y * p.y + p.z * p.z + p.w * p.w +
                   q.x * q.x + q.y * q.y + q.z * q.z + q.w * q.w;
        for (int m = 32; m; m >>= 1) ss += __shfl_xor(ss, m, 64);
        float inv = 1.f / fmaxf(sqrtf(ss), 1e-12f);
        a0 += p.x * inv; a1 += p.y * inv; a2 += p.z * inv; a3 += p.w * inv;
        a4 += q.x * inv; a5 += q.y * inv; a6 += q.z * inv; a7 += q.w * inv;
    };

    for (int j = start + wave; j < end; j += 4) add_row(list[c * CAP + j]);

    // ---- boundary-candidate finish (block 0 only) ----
    if (blockIdx.x == 0) {
        int n = (int)min(ccnt_g[c * PAD], (unsigned)CANDCAP);
        int Kr = krem_g[c];
        if (n > 0 && Kr > 0) {
            if (threadIdx.x == 0) wn_s = 0;
            for (int j = threadIdx.x; j < n; j += 256) {
                cb_s[j] = candb[c * CANDCAP + j];
                ci_s[j] = candi[c * CANDCAP + j];
            }
            __syncthreads();
            for (int j = threadIdx.x; j < n; j += 256) {
                unsigned bj = cb_s[j]; int ij = ci_s[j];
                int r = 0;
                for (int k = 0; k < n; ++k) {
                    unsigned bk = cb_s[k]; int ik = ci_s[k];
                    r += (bk < bj || (bk == bj && ik < ij)) ? 1 : 0;
                }
                if (r < Kr) { int pos = atomicAdd(&wn_s, 1); win[pos] = ij; }
            }
            __syncthreads();
            int wn = wn_s;
            for (int j = wave; j < wn; j += 4) add_row(win[j]);
        }
    }

    *(float4*)&wsum[wave][lane * 8]     = make_float4(a0, a1, a2, a3);
    *(float4*)&wsum[wave][lane * 8 + 4] = make_float4(a4, a5, a6, a7);
    __syncthreads();
    for (int i = threadIdx.x; i < D; i += 256) {
        float t = wsum[0][i] + wsum[1][i] + wsum[2][i] + wsum[3][i];
        if (t != 0.f) atomicAdd(&Wc[c * D + i], t);
    }
}

// ---------------------------------------------------------------------------
// K4: out = feature @ (Wc^T column-normalized). Norms computed in-block.
// ---------------------------------------------------------------------------
__global__ __launch_bounds__(256) void k_out(
    const float* __restrict__ feature, const float* __restrict__ Wc,
    float* __restrict__ out, int B)
{
    __shared__ float w_s[C * D];
    __shared__ float inv_s[C];
    int tid = threadIdx.x;
    for (int i = tid; i < C * D; i += 256) w_s[i] = Wc[i];
    __syncthreads();
    int wave = tid >> 6, lane = tid & 63;
    for (int c = wave; c < C; c += 4) {
        const float* w = w_s + c * D + lane * 8;
        float ss = 0.f;
        for (int k = 0; k < 8; ++k) ss += w[k] * w[k];
        for (int m = 32; m; m >>= 1) ss += __shfl_xor(ss, m, 64);
        if (lane == 0) inv_s[c] = 1.f / fmaxf(sqrtf(ss), 1e-12f);
    }
    __syncthreads();
    for (int row = blockIdx.x * 4 + wave; row < B; row += gridDim.x * 4) {
        const float* f = feature + (size_t)row * D;
        float4 f0 = *(const float4*)(f + lane * 8);
        float4 f1 = *(const float4*)(f + lane * 8 + 4);
        for (int c = 0; c < C; ++c) {
            const float* w = w_s + c * D + lane * 8;
            float s = f0.x * w[0] + f0.y * w[1] + f0.z * w[2] + f0.w * w[3] +
                      f1.x * w[4] + f1.y * w[5] + f1.z * w[6] + f1.w * w[7];
            for (int m = 32; m; m >>= 1) s += __shfl_xor(s, m, 64);
            if (lane == 0) out[(size_t)row * C + c] = s * inv_s[c];
        }
    }
}

// ---------------------------------------------------------------------------
extern "C" void kernel_launch(void* const* d_in, const int* in_sizes, int n_in,
                              void* d_out, int out_size, void* d_ws, size_t ws_size,
                              hipStream_t stream)
{
    (void)n_in; (void)out_size; (void)ws_size;
    const float* feature  = (const float*)d_in[0];
    const float* clf_w    = (const float*)d_in[1];
    const float* clf_b    = (const float*)d_in[2];
    const float* supports = (const float*)d_in[3];
    const float* ent_bank = (const float*)d_in[4];
    const int*   labels   = (const int*)d_in[5];
    const int*   fk       = (const int*)d_in[6];
    int B  = in_sizes[0] / D;
    int N  = in_sizes[4];
    int NT = N + B;

    char* ws = (char*)d_ws;
    size_t o = 0;
    auto align256 = [&](size_t x) { return (x + 255) & ~(size_t)255; };
    // ---- zeroed region (one small memset) ----
    unsigned* hist16  = (unsigned*)(ws + o); o = align256(o + (size_t)C * 65536 * 4);
    unsigned* ghist8  = (unsigned*)(ws + o); o = align256(o + (size_t)C * 256 * 4);
    float*    Wc      = (float*)(ws + o);    o = align256(o + (size_t)C * D * 4);
    int*      cnt_g   = (int*)(ws + o);      o = align256(o + (size_t)C * PAD * 4);
    unsigned* ccnt_g  = (unsigned*)(ws + o); o = align256(o + (size_t)C * PAD * 4);
    size_t zero_bytes = o;
    // ---- non-zeroed region (always fully written before read) ----
    float*    ent_new = (float*)(ws + o);    o = align256(o + (size_t)B * 4);
    int*      yhat    = (int*)(ws + o);      o = align256(o + (size_t)B * 4);
    int*      krem_g  = (int*)(ws + o);      o = align256(o + 32 * 4);
    int*      list    = (int*)(ws + o);      o = align256(o + (size_t)C * CAP * 4);
    unsigned* candb   = (unsigned*)(ws + o); o = align256(o + (size_t)C * CANDCAP * 4);
    int*      candi   = (int*)(ws + o);      o = align256(o + (size_t)C * CANDCAP * 4);
    float*    out     = (float*)d_out;

    hipMemsetAsync(ws, 0, zero_bytes, stream);

    int cb = (B + 3) / 4; if (cb > 1024) cb = 1024;
    int fb = cb; int bankb = ((N >> 2) + 255) / 256; if (bankb > fb) fb = bankb;
    int sgc = ((NT >> 2) + 255) / 256;                 // compact grid

    k_front<<<fb, 256, 0, stream>>>(feature, clf_w, clf_b, ent_bank, labels,
                                    ent_new, yhat, hist16, ghist8, N, B);
    k_compact<<<sgc, 256, 0, stream>>>(ent_bank, labels, ent_new, yhat,
                                       ghist8, hist16, fk, krem_g,
                                       cnt_g, list, ccnt_g, candb, candi, N, B);
    k_accum<<<dim3(32, C), 256, 0, stream>>>(supports, feature, list, cnt_g,
                                             ccnt_g, candb, candi, krem_g, Wc, N);
    k_out<<<cb, 256, 0, stream>>>(feature, Wc, out, B);
}